// Round 1
// baseline (121.832 us; speedup 1.0000x reference)
//
#include <hip/hip_runtime.h>

// Problem constants (fixed by setup_inputs)
#define BATCHES   8
#define N_PER     8192
#define M_PER     2048
#define C_FEAT    32
#define KNN       32
#define R2        0.04f            // 0.2^2
#define M_TOT     (BATCHES * M_PER)            // 16384
#define FEAT_OUT  (3 + C_FEAT)                 // 35
#define OUT_FEAT_SZ ((size_t)M_TOT * FEAT_OUT * KNN)   // 18,350,080 floats

// One wave per query, TWO queries per wave sequentially. 2048 blocks x 4 waves
// = 8192 wave-slots = exactly one fully-resident generation (8 blocks/CU at
// 32 waves/CU), so there is no second-generation launch bubble; query #2's
// phase-1 compute overlaps query #1's non-temporal store drain within the
// same wave (stores are fire-and-forget).
// Phase 1 tests 256 candidates/iter (4 per lane) with a one-chunk-ahead
// prefetch — processing (~300cyc) > L2 latency, so the chain is
// compute-gated, not load-gated. Batch->XCD block swizzle keeps each XCD's
// L2 on a single batch (xyz 98KB + feat 1MB < 4MB). All output stores are
// non-temporal so the 75MB write-once stream doesn't evict the gather
// working set from L2.
__global__ __launch_bounds__(256) void sqag_fused_kernel(
    const float* __restrict__ xyz,        // (B*N_PER, 3)
    const float* __restrict__ new_xyz,    // (B*M_PER, 3)
    const float* __restrict__ features,   // (B*N_PER, C_FEAT)
    float* __restrict__ out)              // feats (M,35,K) then idx (M,K) as float
{
    __shared__ int sidx[4][KNN];

    const int wave = threadIdx.x >> 6;
    const int lane = threadIdx.x & 63;

    // batch->XCD swizzle: consecutive blockIdx round-robin across XCDs;
    // make batch == blockIdx&7 so XCD i mostly serves batch i.
    const int bswz   = blockIdx.x & 7;            // batch
    const int within = blockIdx.x >> 3;           // block within batch [0,256)
    const int b      = bswz;
    const int base   = b * N_PER;
    const float* const pbase = xyz + (size_t)base * 3 + lane * 3;

    #pragma unroll
    for (int qq = 0; qq < 2; ++qq) {
        // local query index in [0, 2048): slot + qq*1024
        const int q = __builtin_amdgcn_readfirstlane(
            b * M_PER + (within * 4 + wave) + qq * (M_PER / 2));

        const float px = new_xyz[q * 3 + 0];
        const float py = new_xyz[q * 3 + 1];
        const float pz = new_xyz[q * 3 + 2];

        int cnt = 0;
        int first = 0;

        // current/next chunk registers: 4 sub-chunks of 64 points each
        float cx[4], cy[4], cz[4];
        const float* p = pbase;
        #pragma unroll
        for (int c = 0; c < 4; ++c) {
            cx[c] = p[c * 192 + 0];
            cy[c] = p[c * 192 + 1];
            cz[c] = p[c * 192 + 2];
        }

        for (int cb = 0;;) {
            const bool more = (cb + 256) < N_PER;      // wave-uniform
            float nx[4], ny[4], nz[4];
            if (more) {
                const float* pn = p + 768;             // +256 points
                #pragma unroll
                for (int c = 0; c < 4; ++c) {
                    nx[c] = pn[c * 192 + 0];
                    ny[c] = pn[c * 192 + 1];
                    nz[c] = pn[c * 192 + 2];
                }
            }

            // test current 256 candidates — match numpy rounding (no FMA)
            unsigned long long m[4];
            bool in[4];
            #pragma unroll
            for (int c = 0; c < 4; ++c) {
                const float dx = px - cx[c];
                const float dy = py - cy[c];
                const float dz = pz - cz[c];
                const float d2 = __fadd_rn(__fadd_rn(__fmul_rn(dx, dx),
                                                     __fmul_rn(dy, dy)),
                                           __fmul_rn(dz, dz));
                in[c] = d2 < R2;
                m[c]  = __ballot(in[c]);
            }

            if (cnt == 0) {
                if      (m[0]) first = cb +       (__ffsll((long long)m[0]) - 1);
                else if (m[1]) first = cb +  64 + (__ffsll((long long)m[1]) - 1);
                else if (m[2]) first = cb + 128 + (__ffsll((long long)m[2]) - 1);
                else if (m[3]) first = cb + 192 + (__ffsll((long long)m[3]) - 1);
            }

            int pre = cnt;
            #pragma unroll
            for (int c = 0; c < 4; ++c) {
                if (in[c]) {
                    const int r = pre + (int)__builtin_amdgcn_mbcnt_hi(
                        (unsigned)(m[c] >> 32),
                        __builtin_amdgcn_mbcnt_lo((unsigned)m[c], 0u));
                    if (r < KNN) sidx[wave][r] = cb + c * 64 + lane;
                }
                pre += __popcll(m[c]);
            }
            cnt = pre;

            if (cnt >= KNN || !more) break;            // wave-uniform
            p += 768;
            cb += 256;
            #pragma unroll
            for (int c = 0; c < 4; ++c) {
                cx[c] = nx[c]; cy[c] = ny[c]; cz[c] = nz[c];
            }
        }

        // pad slots [cnt, KNN) with first hit (0 if empty)
        const int pad = (cnt == 0) ? 0 : first;
        if (lane >= cnt && lane < KNN) sidx[wave][lane] = pad;
        const float zf = (cnt == 0) ? 0.0f : 1.0f;

        // ---- phase 2: full wave, half-wave per feature half ----
        const int k    = lane & 31;            // slot
        const int half = lane >> 5;            // feature half

        const int li = sidx[wave][k];          // broadcast pair-read
        const int gi = base + li;

        const float4* f = (const float4*)(features + (size_t)gi * C_FEAT + half * 16);
        const float4 v0 = f[0];
        const float4 v1 = f[1];
        const float4 v2 = f[2];
        const float4 v3 = f[3];

        const float gx = xyz[(size_t)gi * 3 + 0] - px;
        const float gy = xyz[(size_t)gi * 3 + 1] - py;
        const float gz = xyz[(size_t)gi * 3 + 2] - pz;

        float* o = out + (size_t)q * (FEAT_OUT * KNN);
        if (half == 0) {
            __builtin_nontemporal_store(zf * gx, &o[0 * KNN + k]);
            __builtin_nontemporal_store(zf * gy, &o[1 * KNN + k]);
            __builtin_nontemporal_store(zf * gz, &o[2 * KNN + k]);
            __builtin_nontemporal_store((float)li,
                                        &out[OUT_FEAT_SZ + (size_t)q * KNN + k]);
        }

        const int jb = 3 + half * 16;
        __builtin_nontemporal_store(zf * v0.x, &o[(jb +  0) * KNN + k]);
        __builtin_nontemporal_store(zf * v0.y, &o[(jb +  1) * KNN + k]);
        __builtin_nontemporal_store(zf * v0.z, &o[(jb +  2) * KNN + k]);
        __builtin_nontemporal_store(zf * v0.w, &o[(jb +  3) * KNN + k]);
        __builtin_nontemporal_store(zf * v1.x, &o[(jb +  4) * KNN + k]);
        __builtin_nontemporal_store(zf * v1.y, &o[(jb +  5) * KNN + k]);
        __builtin_nontemporal_store(zf * v1.z, &o[(jb +  6) * KNN + k]);
        __builtin_nontemporal_store(zf * v1.w, &o[(jb +  7) * KNN + k]);
        __builtin_nontemporal_store(zf * v2.x, &o[(jb +  8) * KNN + k]);
        __builtin_nontemporal_store(zf * v2.y, &o[(jb +  9) * KNN + k]);
        __builtin_nontemporal_store(zf * v2.z, &o[(jb + 10) * KNN + k]);
        __builtin_nontemporal_store(zf * v2.w, &o[(jb + 11) * KNN + k]);
        __builtin_nontemporal_store(zf * v3.x, &o[(jb + 12) * KNN + k]);
        __builtin_nontemporal_store(zf * v3.y, &o[(jb + 13) * KNN + k]);
        __builtin_nontemporal_store(zf * v3.z, &o[(jb + 14) * KNN + k]);
        __builtin_nontemporal_store(zf * v3.w, &o[(jb + 15) * KNN + k]);
    }
}

extern "C" void kernel_launch(void* const* d_in, const int* in_sizes, int n_in,
                              void* d_out, int out_size, void* d_ws, size_t ws_size,
                              hipStream_t stream) {
    const float* xyz      = (const float*)d_in[0];
    // d_in[1] = xyz_batch_cnt (constant 8192 each) — unused
    const float* new_xyz  = (const float*)d_in[2];
    // d_in[3] = new_xyz_batch_cnt (constant 2048 each) — unused
    const float* features = (const float*)d_in[4];
    float* out = (float*)d_out;

    // Two queries per wave, 4 waves per block -> 2048 blocks (one generation)
    sqag_fused_kernel<<<M_TOT / 8, 256, 0, stream>>>(xyz, new_xyz, features, out);
}

// Round 2
// 116.528 us; speedup vs baseline: 1.0455x; 1.0455x over previous
//
#include <hip/hip_runtime.h>

// Problem constants (fixed by setup_inputs)
#define BATCHES   8
#define N_PER     8192
#define M_PER     2048
#define C_FEAT    32
#define KNN       32
#define R2        0.04f            // 0.2^2
#define M_TOT     (BATCHES * M_PER)            // 16384
#define N_TOT     (BATCHES * N_PER)            // 65536
#define FEAT_OUT  (3 + C_FEAT)                 // 35
#define OUT_FEAT_SZ ((size_t)M_TOT * FEAT_OUT * KNN)   // 18,350,080 floats
#define WS_NEEDED ((size_t)3 * N_TOT * sizeof(float))  // 786,432 B

// One-time AoS->SoA transpose of xyz into workspace: xs[65536]|ys|zs.
// Reads are stride-12 (paid once); writes fully dense.
__global__ __launch_bounds__(256) void transpose_xyz_kernel(
    const float* __restrict__ xyz, float* __restrict__ ws)
{
    const int i = blockIdx.x * 256 + threadIdx.x;   // point id, grid covers N_TOT
    const float x = xyz[i * 3 + 0];
    const float y = xyz[i * 3 + 1];
    const float z = xyz[i * 3 + 2];
    ws[i]             = x;
    ws[N_TOT + i]     = y;
    ws[2 * N_TOT + i] = z;
}

// One wave per query (reverted from 2-q/wave: static pairing doubled the
// boundary-query tail; dynamic dispatch of 4096 blocks load-balances it).
// Phase 1 tests 256 candidates/iter (4 per lane) with one-chunk-ahead
// prefetch. SOA=true reads the transposed xs/ys/zs — dense dword loads touch
// 4 L1 lines/instr instead of 12 (stride-12 AoS), un-gating phase-1 from L1
// line throughput so it hides under the store stream. Batch->XCD swizzle
// keeps each XCD's L2 on one batch. Output stores non-temporal (write-once
// 75MB stream must not evict the gather set from L2).
template <bool SOA>
__global__ __launch_bounds__(256) void sqag_fused_kernel(
    const float* __restrict__ xyz,        // (B*N_PER, 3)
    const float* __restrict__ new_xyz,    // (B*M_PER, 3)
    const float* __restrict__ features,   // (B*N_PER, C_FEAT)
    const float* __restrict__ ws,         // SoA xs|ys|zs (valid iff SOA)
    float* __restrict__ out)              // feats (M,35,K) then idx (M,K) as float
{
    __shared__ int sidx[4][KNN];

    const int wave = threadIdx.x >> 6;
    const int lane = threadIdx.x & 63;

    // batch->XCD swizzle: consecutive blockIdx round-robin across XCDs;
    // make batch == blockIdx&7 so XCD i mostly serves batch i.
    const int bswz   = blockIdx.x & 7;            // batch
    const int within = blockIdx.x >> 3;           // block within batch [0,512)
    const int q = __builtin_amdgcn_readfirstlane(
        (bswz * (M_PER / 4) + within) * 4 + wave);
    const int b    = q >> 11;                     // == bswz
    const int base = b * N_PER;

    const float px = new_xyz[q * 3 + 0];
    const float py = new_xyz[q * 3 + 1];
    const float pz = new_xyz[q * 3 + 2];

    int cnt = 0;
    int first = 0;

    const float* xs = ws;
    const float* ys = ws + N_TOT;
    const float* zs = ws + 2 * N_TOT;

    // current/next chunk registers: 4 sub-chunks of 64 points each
    float cx[4], cy[4], cz[4];
    const float* p = xyz + (size_t)base * 3 + lane * 3;   // AoS path
    int off = base + lane;                                 // SoA path
    #pragma unroll
    for (int c = 0; c < 4; ++c) {
        if (SOA) {
            cx[c] = xs[off + c * 64];
            cy[c] = ys[off + c * 64];
            cz[c] = zs[off + c * 64];
        } else {
            cx[c] = p[c * 192 + 0];
            cy[c] = p[c * 192 + 1];
            cz[c] = p[c * 192 + 2];
        }
    }

    for (int cb = 0;;) {
        const bool more = (cb + 256) < N_PER;      // wave-uniform
        float nx[4], ny[4], nz[4];
        if (more) {
            #pragma unroll
            for (int c = 0; c < 4; ++c) {
                if (SOA) {
                    nx[c] = xs[off + 256 + c * 64];
                    ny[c] = ys[off + 256 + c * 64];
                    nz[c] = zs[off + 256 + c * 64];
                } else {
                    const float* pn = p + 768;
                    nx[c] = pn[c * 192 + 0];
                    ny[c] = pn[c * 192 + 1];
                    nz[c] = pn[c * 192 + 2];
                }
            }
        }

        // test current 256 candidates — match numpy rounding (no FMA)
        unsigned long long m[4];
        bool in[4];
        #pragma unroll
        for (int c = 0; c < 4; ++c) {
            const float dx = px - cx[c];
            const float dy = py - cy[c];
            const float dz = pz - cz[c];
            const float d2 = __fadd_rn(__fadd_rn(__fmul_rn(dx, dx),
                                                 __fmul_rn(dy, dy)),
                                       __fmul_rn(dz, dz));
            in[c] = d2 < R2;
            m[c]  = __ballot(in[c]);
        }

        if (cnt == 0) {
            if      (m[0]) first = cb +       (__ffsll((long long)m[0]) - 1);
            else if (m[1]) first = cb +  64 + (__ffsll((long long)m[1]) - 1);
            else if (m[2]) first = cb + 128 + (__ffsll((long long)m[2]) - 1);
            else if (m[3]) first = cb + 192 + (__ffsll((long long)m[3]) - 1);
        }

        int pre = cnt;
        #pragma unroll
        for (int c = 0; c < 4; ++c) {
            if (in[c]) {
                const int r = pre + (int)__builtin_amdgcn_mbcnt_hi(
                    (unsigned)(m[c] >> 32),
                    __builtin_amdgcn_mbcnt_lo((unsigned)m[c], 0u));
                if (r < KNN) sidx[wave][r] = cb + c * 64 + lane;
            }
            pre += __popcll(m[c]);
        }
        cnt = pre;

        if (cnt >= KNN || !more) break;            // wave-uniform
        p += 768;
        off += 256;
        cb += 256;
        #pragma unroll
        for (int c = 0; c < 4; ++c) {
            cx[c] = nx[c]; cy[c] = ny[c]; cz[c] = nz[c];
        }
    }

    // pad slots [cnt, KNN) with first hit (0 if empty)
    const int pad = (cnt == 0) ? 0 : first;
    if (lane >= cnt && lane < KNN) sidx[wave][lane] = pad;
    const float zf = (cnt == 0) ? 0.0f : 1.0f;

    // ---- phase 2: full wave, half-wave per feature half ----
    const int k    = lane & 31;            // slot
    const int half = lane >> 5;            // feature half

    const int li = sidx[wave][k];          // broadcast pair-read
    const int gi = base + li;

    const float4* f = (const float4*)(features + (size_t)gi * C_FEAT + half * 16);
    const float4 v0 = f[0];
    const float4 v1 = f[1];
    const float4 v2 = f[2];
    const float4 v3 = f[3];

    // gather stays AoS: one neighbor's 12B spans 1-2 lines vs 3 with SoA
    const float gx = xyz[(size_t)gi * 3 + 0] - px;
    const float gy = xyz[(size_t)gi * 3 + 1] - py;
    const float gz = xyz[(size_t)gi * 3 + 2] - pz;

    float* o = out + (size_t)q * (FEAT_OUT * KNN);
    if (half == 0) {
        __builtin_nontemporal_store(zf * gx, &o[0 * KNN + k]);
        __builtin_nontemporal_store(zf * gy, &o[1 * KNN + k]);
        __builtin_nontemporal_store(zf * gz, &o[2 * KNN + k]);
        __builtin_nontemporal_store((float)li,
                                    &out[OUT_FEAT_SZ + (size_t)q * KNN + k]);
    }

    const int jb = 3 + half * 16;
    __builtin_nontemporal_store(zf * v0.x, &o[(jb +  0) * KNN + k]);
    __builtin_nontemporal_store(zf * v0.y, &o[(jb +  1) * KNN + k]);
    __builtin_nontemporal_store(zf * v0.z, &o[(jb +  2) * KNN + k]);
    __builtin_nontemporal_store(zf * v0.w, &o[(jb +  3) * KNN + k]);
    __builtin_nontemporal_store(zf * v1.x, &o[(jb +  4) * KNN + k]);
    __builtin_nontemporal_store(zf * v1.y, &o[(jb +  5) * KNN + k]);
    __builtin_nontemporal_store(zf * v1.z, &o[(jb +  6) * KNN + k]);
    __builtin_nontemporal_store(zf * v1.w, &o[(jb +  7) * KNN + k]);
    __builtin_nontemporal_store(zf * v2.x, &o[(jb +  8) * KNN + k]);
    __builtin_nontemporal_store(zf * v2.y, &o[(jb +  9) * KNN + k]);
    __builtin_nontemporal_store(zf * v2.z, &o[(jb + 10) * KNN + k]);
    __builtin_nontemporal_store(zf * v2.w, &o[(jb + 11) * KNN + k]);
    __builtin_nontemporal_store(zf * v3.x, &o[(jb + 12) * KNN + k]);
    __builtin_nontemporal_store(zf * v3.y, &o[(jb + 13) * KNN + k]);
    __builtin_nontemporal_store(zf * v3.z, &o[(jb + 14) * KNN + k]);
    __builtin_nontemporal_store(zf * v3.w, &o[(jb + 15) * KNN + k]);
}

extern "C" void kernel_launch(void* const* d_in, const int* in_sizes, int n_in,
                              void* d_out, int out_size, void* d_ws, size_t ws_size,
                              hipStream_t stream) {
    const float* xyz      = (const float*)d_in[0];
    // d_in[1] = xyz_batch_cnt (constant 8192 each) — unused
    const float* new_xyz  = (const float*)d_in[2];
    // d_in[3] = new_xyz_batch_cnt (constant 2048 each) — unused
    const float* features = (const float*)d_in[4];
    float* out = (float*)d_out;

    if (ws_size >= WS_NEEDED && d_ws != nullptr) {
        float* ws = (float*)d_ws;
        transpose_xyz_kernel<<<N_TOT / 256, 256, 0, stream>>>(xyz, ws);
        sqag_fused_kernel<true><<<M_TOT / 4, 256, 0, stream>>>(
            xyz, new_xyz, features, ws, out);
    } else {
        // workspace too small: proven AoS path
        sqag_fused_kernel<false><<<M_TOT / 4, 256, 0, stream>>>(
            xyz, new_xyz, features, nullptr, out);
    }
}